// Round 11
// baseline (3230.792 us; speedup 1.0000x reference)
//
#include <hip/hip_runtime.h>
#include <stdint.h>

// Problem constants (fixed shapes)
#define TT 8192      // tokens = B*S
#define HH 2048      // hidden dim
#define II 1408      // intermediate dim
#define NE 8         // experts
#define NROWS (TT*2) // (token, slot) rows = 16384
#define BM 256       // row tile (512-thread blocks, 8 waves)
#define BK 64        // k tile
#define BND 128      // k_down N tile
#define MAXS 80      // max slots at BM=256 (<=72 used; 80 % 8 == 0)
#define NKT_GU (HH/BK)   // 32
#define NKT_DN (II/BK)   // 22
#define NYT_GU (II/64)   // 22  N-tiles in k_gu (N=64 per B-matrix, gate+up)
#define NYT_DN (HH/BND)  // 16  N-tiles in k_down
#define SPX (MAXS/8)     // 10 slots per XCD

typedef unsigned short u16;
typedef __attribute__((ext_vector_type(8))) __bf16 bhalf8;
typedef __attribute__((ext_vector_type(4))) float f32x4;
typedef __attribute__((ext_vector_type(4))) float float4v;
typedef __attribute__((ext_vector_type(4))) int int4v;

__device__ __forceinline__ u16 f2bf(float f) {
  union { float f; unsigned u; } v; v.f = f;
  return (u16)((v.u + 0x7FFFu + ((v.u >> 16) & 1u)) >> 16);  // RNE
}

__device__ __forceinline__ void gld16(const void* g, void* l) {
  __builtin_amdgcn_global_load_lds(
      (const __attribute__((address_space(1))) unsigned int*)g,
      (__attribute__((address_space(3))) unsigned int*)l, 16, 0, 0);
}

// ---------------- hidden_states fp32 -> bf16 ----------------
__global__ __launch_bounds__(256) void k_cvt_hs(const float* __restrict__ in,
                                                u16* __restrict__ out) {
  size_t i = ((size_t)blockIdx.x * 256 + threadIdx.x) * 8;
  float4v a = *(const float4v*)(in + i);
  float4v b = *(const float4v*)(in + i + 4);
  u16 o[8];
  o[0] = f2bf(a.x); o[1] = f2bf(a.y); o[2] = f2bf(a.z); o[3] = f2bf(a.w);
  o[4] = f2bf(b.x); o[5] = f2bf(b.y); o[6] = f2bf(b.z); o[7] = f2bf(b.w);
  *(int4v*)(out + i) = *(const int4v*)o;
}

// ------- down weight fp32 [E][R][C] -> bf16 transposed [E][C][R] -------
__global__ __launch_bounds__(256) void k_tconv(const float* __restrict__ in,
                                               u16* __restrict__ out,
                                               int R, int C) {
  __shared__ float t[64][65];
  int e = blockIdx.z;
  int r0 = blockIdx.y * 64, c0 = blockIdx.x * 64;
  const float* ip = in + (size_t)e * R * C;
  u16* op = out + (size_t)e * R * C;
  int tid = threadIdx.x;
  int rr = tid >> 4, c4 = (tid & 15) * 4;
#pragma unroll
  for (int j = 0; j < 4; ++j) {
    float4v v = *(const float4v*)&ip[(size_t)(r0 + rr + 16 * j) * C + c0 + c4];
    t[rr + 16 * j][c4 + 0] = v.x;
    t[rr + 16 * j][c4 + 1] = v.y;
    t[rr + 16 * j][c4 + 2] = v.z;
    t[rr + 16 * j][c4 + 3] = v.w;
  }
  __syncthreads();
  int cc = tid >> 2, rb = (tid & 3) * 16;
  u16 buf[16];
#pragma unroll
  for (int i = 0; i < 16; ++i) buf[i] = f2bf(t[rb + i][cc]);
  u16* p = op + (size_t)(c0 + cc) * R + r0 + rb;
  *(int4v*)p = *(const int4v*)&buf[0];
  *(int4v*)(p + 8) = *(const int4v*)&buf[8];
}

// ------- gate+up fp32 [E][H][I] -> bf16 [E][I][H], one fused launch -------
__global__ __launch_bounds__(256) void k_tconv2(const float* __restrict__ gw,
                                                const float* __restrict__ uw,
                                                u16* __restrict__ gwt,
                                                u16* __restrict__ uwt) {
  __shared__ float t[64][65];
  const int R = HH, C = II;
  int z = blockIdx.z;
  int e = z & 7;
  const float* in = (z < 8) ? gw : uw;
  u16* out = (z < 8) ? gwt : uwt;
  int r0 = blockIdx.y * 64, c0 = blockIdx.x * 64;
  const float* ip = in + (size_t)e * R * C;
  u16* op = out + (size_t)e * R * C;
  int tid = threadIdx.x;
  int rr = tid >> 4, c4 = (tid & 15) * 4;
#pragma unroll
  for (int j = 0; j < 4; ++j) {
    float4v v = *(const float4v*)&ip[(size_t)(r0 + rr + 16 * j) * C + c0 + c4];
    t[rr + 16 * j][c4 + 0] = v.x;
    t[rr + 16 * j][c4 + 1] = v.y;
    t[rr + 16 * j][c4 + 2] = v.z;
    t[rr + 16 * j][c4 + 3] = v.w;
  }
  __syncthreads();
  int cc = tid >> 2, rb = (tid & 3) * 16;
  u16 buf[16];
#pragma unroll
  for (int i = 0; i < 16; ++i) buf[i] = f2bf(t[rb + i][cc]);
  u16* p = op + (size_t)(c0 + cc) * R + r0 + rb;
  *(int4v*)p = *(const int4v*)&buf[0];
  *(int4v*)(p + 8) = *(const int4v*)&buf[8];
}

// ---------------- routing: gather rows by expert (256-row slots) ----------------
__global__ __launch_bounds__(256) void k_route(const int* __restrict__ sel,
                                               const float* __restrict__ rw,
                                               int* __restrict__ token_idx,
                                               float* __restrict__ wrow,
                                               int* __restrict__ s_e,
                                               int* __restrict__ s_rs,
                                               int* __restrict__ s_rows) {
  __shared__ int cnt[NE], offs[NE + 1], cursor[NE];
  int tid = threadIdx.x;
  if (tid < NE) cnt[tid] = 0;
  __syncthreads();
  for (int i = tid; i < NROWS; i += 256) atomicAdd(&cnt[sel[i]], 1);
  __syncthreads();
  if (tid == 0) {
    int o = 0;
    for (int e = 0; e < NE; ++e) { offs[e] = o; o += cnt[e]; }
    offs[NE] = o;
    int ns = 0;
    for (int e = 0; e < NE; ++e) {
      for (int t = 0; t < cnt[e]; t += BM) {
        s_e[ns] = e;
        s_rs[ns] = offs[e] + t;
        s_rows[ns] = (cnt[e] - t < BM) ? (cnt[e] - t) : BM;
        ns++;
      }
    }
    for (; ns < MAXS; ++ns) s_rows[ns] = 0;
  }
  __syncthreads();
  if (tid < NE) cursor[tid] = offs[tid];
  __syncthreads();
  for (int i = tid; i < NROWS; i += 256) {
    int e = sel[i];
    int r = atomicAdd(&cursor[e], 1);
    token_idx[r] = i >> 1;   // token id
    wrow[r] = rw[i];         // routing weight for this slot
  }
}

// ---------------- gate/up GEMM + SwiGLU (BM=256, 512 thr, m97 structure) --------
// Single-buffered LDS 48 KB -> 3 blocks/CU = 24 waves/CU. 8 waves as 4M x 2N.
// 1D grid, XCD-aware bijective swizzle (80 slots = 8 XCD x 10).
__global__ __launch_bounds__(512, 6) void k_gu(const u16* __restrict__ hsb,
                                               const u16* __restrict__ gwt,
                                               const u16* __restrict__ uwt,
                                               const int* __restrict__ token_idx,
                                               const float* __restrict__ wrow,
                                               const int* __restrict__ s_e,
                                               const int* __restrict__ s_rs,
                                               const int* __restrict__ s_rows,
                                               u16* __restrict__ act) {
  int f = blockIdx.x;
  int xcd = f & 7;
  int pos = f >> 3;                 // 0..219
  int slot = xcd * SPX + pos / NYT_GU;
  int ytile = pos % NYT_GU;
  int nrows = s_rows[slot];
  if (nrows == 0) return;
  int e = s_e[slot];
  int row0 = s_rs[slot];
  int i0 = ytile * 64;

  __shared__ alignas(16) u16 As[BM][BK];   // 32 KB
  __shared__ alignas(16) u16 Bg[64][BK];   // 8 KB
  __shared__ alignas(16) u16 Bu[64][BK];   // 8 KB  -> 48 KB total

  int tid = threadIdx.x;
  int lane = tid & 63;
  int wid = tid >> 6;          // 0..7
  int l8 = lane >> 3;
  int c8 = lane & 7;
  int cs = c8 ^ l8;            // swizzled source chunk (dest LDS linear, rule #21)

  // A staging: wave wid covers rows wid*32 + j*8 + l8 (8 waves x 32 = 256)
  const u16* agp[4];
#pragma unroll
  for (int j = 0; j < 4; ++j) {
    int gr = row0 + wid * 32 + j * 8 + l8;
    if (gr > NROWS - 1) gr = NROWS - 1;
    int tok = token_idx[gr];
    agp[j] = hsb + (size_t)tok * HH + cs * 8;
  }
  // B staging: wave wid covers rows wid*8 + l8 of each 64-row panel
  size_t boff = ((size_t)e * II + i0 + wid * 8 + l8) * HH + cs * 8;
  const u16* ggp = gwt + boff;
  const u16* ugp = uwt + boff;

  int wm = wid >> 1, wn = wid & 1;   // 4M x 2N wave grid
  int l15 = lane & 15, l16 = lane >> 4;

  f32x4 accg[4][2], accu[4][2];
#pragma unroll
  for (int a = 0; a < 4; ++a)
#pragma unroll
    for (int b = 0; b < 2; ++b) { accg[a][b] = (f32x4)0.0f; accu[a][b] = (f32x4)0.0f; }

  for (int kt = 0; kt < NKT_GU; ++kt) {
    int k0 = kt * BK;
#pragma unroll
    for (int j = 0; j < 4; ++j) gld16(agp[j] + k0, &As[wid * 32 + j * 8][0]);
    gld16(ggp + k0, &Bg[wid * 8][0]);
    gld16(ugp + k0, &Bu[wid * 8][0]);
    __syncthreads();
#pragma unroll
    for (int ks = 0; ks < 2; ++ks) {
      bhalf8 af[4], bgf[2], buf_[2];
#pragma unroll
      for (int mf = 0; mf < 4; ++mf) {
        int row = wm * 64 + mf * 16 + l15;
        int c = (ks * 4 + l16) ^ (row & 7);
        af[mf] = *(const bhalf8*)&As[row][c * 8];
      }
#pragma unroll
      for (int nf = 0; nf < 2; ++nf) {
        int row = wn * 32 + nf * 16 + l15;
        int c = (ks * 4 + l16) ^ (row & 7);
        bgf[nf] = *(const bhalf8*)&Bg[row][c * 8];
        buf_[nf] = *(const bhalf8*)&Bu[row][c * 8];
      }
#pragma unroll
      for (int mf = 0; mf < 4; ++mf)
#pragma unroll
        for (int nf = 0; nf < 2; ++nf) {
          accg[mf][nf] = __builtin_amdgcn_mfma_f32_16x16x32_bf16(af[mf], bgf[nf], accg[mf][nf], 0, 0, 0);
          accu[mf][nf] = __builtin_amdgcn_mfma_f32_16x16x32_bf16(af[mf], buf_[nf], accu[mf][nf], 0, 0, 0);
        }
    }
    __syncthreads();
  }

  // epilogue: act = w * silu(g) * u
#pragma unroll
  for (int mf = 0; mf < 4; ++mf) {
#pragma unroll
    for (int j = 0; j < 4; ++j) {
      int lm = wm * 64 + mf * 16 + l16 * 4 + j;
      if (lm < nrows) {
        int gr = row0 + lm;
        float w = wrow[gr];
        size_t base = (size_t)gr * II + i0 + wn * 32 + l15;
#pragma unroll
        for (int nf = 0; nf < 2; ++nf) {
          float g = accg[mf][nf][j];
          float u = accu[mf][nf][j];
          float s = g / (1.0f + __expf(-g));
          act[base + nf * 16] = f2bf(s * u * w);
        }
      }
    }
  }
}

// ---------------- down GEMM (BM=256, BN=128, 512 thr) + scatter-add -------------
__global__ __launch_bounds__(512, 6) void k_down(const u16* __restrict__ act,
                                                 const u16* __restrict__ dwt,
                                                 const int* __restrict__ token_idx,
                                                 const int* __restrict__ s_e,
                                                 const int* __restrict__ s_rs,
                                                 const int* __restrict__ s_rows,
                                                 float* __restrict__ out) {
  int f = blockIdx.x;
  int xcd = f & 7;
  int pos = f >> 3;                 // 0..159
  int slot = xcd * SPX + pos / NYT_DN;
  int ytile = pos % NYT_DN;
  int nrows = s_rows[slot];
  if (nrows == 0) return;
  int e = s_e[slot];
  int row0 = s_rs[slot];
  int h0 = ytile * BND;

  __shared__ alignas(16) u16 As[BM][BK];    // 32 KB
  __shared__ alignas(16) u16 Bs[BND][BK];   // 16 KB -> 48 KB total

  int tid = threadIdx.x;
  int lane = tid & 63;
  int wid = tid >> 6;
  int l8 = lane >> 3;
  int c8 = lane & 7;
  int cs = c8 ^ l8;

  const u16* agp[4];
#pragma unroll
  for (int j = 0; j < 4; ++j) {
    int gr = row0 + wid * 32 + j * 8 + l8;
    if (gr > NROWS - 1) gr = NROWS - 1;
    agp[j] = act + (size_t)gr * II + cs * 8;
  }
  const u16* bgp[2];
#pragma unroll
  for (int j = 0; j < 2; ++j)
    bgp[j] = dwt + ((size_t)e * HH + h0 + wid * 16 + j * 8 + l8) * II + cs * 8;

  int wm = wid >> 1, wn = wid & 1;   // 4M x 2N, wave tile 64x64
  int l15 = lane & 15, l16 = lane >> 4;

  f32x4 acc[4][4];
#pragma unroll
  for (int a = 0; a < 4; ++a)
#pragma unroll
    for (int b = 0; b < 4; ++b) acc[a][b] = (f32x4)0.0f;

  for (int kt = 0; kt < NKT_DN; ++kt) {
    int k0 = kt * BK;
#pragma unroll
    for (int j = 0; j < 4; ++j) gld16(agp[j] + k0, &As[wid * 32 + j * 8][0]);
#pragma unroll
    for (int j = 0; j < 2; ++j) gld16(bgp[j] + k0, &Bs[wid * 16 + j * 8][0]);
    __syncthreads();
#pragma unroll
    for (int ks = 0; ks < 2; ++ks) {
      bhalf8 af[4], bf[4];
#pragma unroll
      for (int mf = 0; mf < 4; ++mf) {
        int row = wm * 64 + mf * 16 + l15;
        int c = (ks * 4 + l16) ^ (row & 7);
        af[mf] = *(const bhalf8*)&As[row][c * 8];
      }
#pragma unroll
      for (int nf = 0; nf < 4; ++nf) {
        int row = wn * 64 + nf * 16 + l15;
        int c = (ks * 4 + l16) ^ (row & 7);
        bf[nf] = *(const bhalf8*)&Bs[row][c * 8];
      }
#pragma unroll
      for (int mf = 0; mf < 4; ++mf)
#pragma unroll
        for (int nf = 0; nf < 4; ++nf)
          acc[mf][nf] = __builtin_amdgcn_mfma_f32_16x16x32_bf16(af[mf], bf[nf], acc[mf][nf], 0, 0, 0);
    }
    __syncthreads();
  }

#pragma unroll
  for (int mf = 0; mf < 4; ++mf) {
#pragma unroll
    for (int j = 0; j < 4; ++j) {
      int lm = wm * 64 + mf * 16 + l16 * 4 + j;
      if (lm < nrows) {
        int tok = token_idx[row0 + lm];
        size_t base = (size_t)tok * HH + h0 + wn * 64 + l15;
#pragma unroll
        for (int nf = 0; nf < 4; ++nf)
          atomicAdd(&out[base + nf * 16], acc[mf][nf][j]);
      }
    }
  }
}

extern "C" void kernel_launch(void* const* d_in, const int* in_sizes, int n_in,
                              void* d_out, int out_size, void* d_ws, size_t ws_size,
                              hipStream_t stream) {
  const int* sel = (const int*)d_in[0];
  const float* hs = (const float*)d_in[1];
  const float* rw = (const float*)d_in[2];
  const float* gw = (const float*)d_in[3];
  const float* uw = (const float*)d_in[4];
  const float* dw = (const float*)d_in[5];
  float* out = (float*)d_out;

  char* ws = (char*)d_ws;
  size_t o = 0;
  u16* hsb = (u16*)(ws + o); o += (size_t)TT * HH * 2;           // 32 MB
  u16* gwt = (u16*)(ws + o); o += (size_t)NE * HH * II * 2;      // 44 MB
  u16* uwt = (u16*)(ws + o); o += (size_t)NE * HH * II * 2;      // 44 MB
  u16* dwt = (u16*)(ws + o); o += (size_t)NE * HH * II * 2;      // 44 MB
  u16* act = (u16*)(ws + o); o += (size_t)NROWS * II * 2;        // 44 MB
  int* token_idx = (int*)(ws + o); o += (size_t)NROWS * 4;
  float* wrow = (float*)(ws + o); o += (size_t)NROWS * 4;
  int* s_e = (int*)(ws + o); o += MAXS * 4;
  int* s_rs = (int*)(ws + o); o += MAXS * 4;
  int* s_rows = (int*)(ws + o); o += MAXS * 4;
  (void)ws_size; (void)in_sizes; (void)n_in; (void)out_size;

  // fp32 -> bf16 conversions (+ weight transpose to [N][K])
  k_cvt_hs<<<(TT * HH) / 2048, 256, 0, stream>>>(hs, hsb);
  dim3 g1(II / 64, HH / 64, 2 * NE);
  k_tconv2<<<g1, 256, 0, stream>>>(gw, uw, gwt, uwt);
  dim3 g2(HH / 64, II / 64, NE);
  k_tconv<<<g2, 256, 0, stream>>>(dw, dwt, II, HH);

  // routing + zero output
  k_route<<<1, 256, 0, stream>>>(sel, rw, token_idx, wrow, s_e, s_rs, s_rows);
  hipMemsetAsync(d_out, 0, (size_t)TT * HH * 4, stream);

  // gate/up GEMM + SwiGLU  (1D grid, XCD swizzle)
  k_gu<<<MAXS * NYT_GU, 512, 0, stream>>>(hsb, gwt, uwt, token_idx, wrow,
                                          s_e, s_rs, s_rows, act);

  // down GEMM with scatter-add  (1D grid, XCD swizzle)
  k_down<<<MAXS * NYT_DN, 512, 0, stream>>>(act, dwt, token_idx,
                                            s_e, s_rs, s_rows, out);
}

// Round 12
// 563.739 us; speedup vs baseline: 5.7310x; 5.7310x over previous
//
#include <hip/hip_runtime.h>
#include <stdint.h>

// Problem constants (fixed shapes)
#define TT 8192      // tokens = B*S
#define HH 2048      // hidden dim
#define II 1408      // intermediate dim
#define NE 8         // experts
#define NROWS (TT*2) // (token, slot) rows = 16384
#define BM 128       // row tile
#define BK 64        // k tile
#define BND 128      // k_down N tile
#define MAX_SLOTS 144
#define NKT_GU (HH/BK)   // 32
#define NKT_DN (II/BK)   // 22
#define NYT_GU (II/64)   // 22  N-tiles in k_gu (N=64 per B-matrix, gate+up)
#define NYT_DN (HH/BND)  // 16  N-tiles in k_down
#define SPX (MAX_SLOTS/8)  // 18 slots per XCD

typedef unsigned short u16;
typedef __attribute__((ext_vector_type(8))) __bf16 bhalf8;
typedef __attribute__((ext_vector_type(4))) float f32x4;
typedef __attribute__((ext_vector_type(4))) float float4v;
typedef __attribute__((ext_vector_type(4))) int int4v;

__device__ __forceinline__ u16 f2bf(float f) {
  union { float f; unsigned u; } v; v.f = f;
  return (u16)((v.u + 0x7FFFu + ((v.u >> 16) & 1u)) >> 16);  // RNE
}

__device__ __forceinline__ void gld16(const void* g, void* l) {
  __builtin_amdgcn_global_load_lds(
      (const __attribute__((address_space(1))) unsigned int*)g,
      (__attribute__((address_space(3))) unsigned int*)l, 16, 0, 0);
}

// ---------------- hidden_states fp32 -> bf16 ----------------
__global__ __launch_bounds__(256) void k_cvt_hs(const float* __restrict__ in,
                                                u16* __restrict__ out) {
  size_t i = ((size_t)blockIdx.x * 256 + threadIdx.x) * 8;
  float4v a = *(const float4v*)(in + i);
  float4v b = *(const float4v*)(in + i + 4);
  u16 o[8];
  o[0] = f2bf(a.x); o[1] = f2bf(a.y); o[2] = f2bf(a.z); o[3] = f2bf(a.w);
  o[4] = f2bf(b.x); o[5] = f2bf(b.y); o[6] = f2bf(b.z); o[7] = f2bf(b.w);
  *(int4v*)(out + i) = *(const int4v*)o;
}

// ------- down weight fp32 [E][R][C] -> bf16 transposed [E][C][R] -------
__global__ __launch_bounds__(256) void k_tconv(const float* __restrict__ in,
                                               u16* __restrict__ out,
                                               int R, int C) {
  __shared__ float t[64][65];
  int e = blockIdx.z;
  int r0 = blockIdx.y * 64, c0 = blockIdx.x * 64;
  const float* ip = in + (size_t)e * R * C;
  u16* op = out + (size_t)e * R * C;
  int tid = threadIdx.x;
  int rr = tid >> 4, c4 = (tid & 15) * 4;
#pragma unroll
  for (int j = 0; j < 4; ++j) {
    float4v v = *(const float4v*)&ip[(size_t)(r0 + rr + 16 * j) * C + c0 + c4];
    t[rr + 16 * j][c4 + 0] = v.x;
    t[rr + 16 * j][c4 + 1] = v.y;
    t[rr + 16 * j][c4 + 2] = v.z;
    t[rr + 16 * j][c4 + 3] = v.w;
  }
  __syncthreads();
  int cc = tid >> 2, rb = (tid & 3) * 16;
  u16 buf[16];
#pragma unroll
  for (int i = 0; i < 16; ++i) buf[i] = f2bf(t[rb + i][cc]);
  u16* p = op + (size_t)(c0 + cc) * R + r0 + rb;
  *(int4v*)p = *(const int4v*)&buf[0];
  *(int4v*)(p + 8) = *(const int4v*)&buf[8];
}

// ------- gate+up fp32 [E][H][I] -> bf16 [E][I][H], one fused launch -------
__global__ __launch_bounds__(256) void k_tconv2(const float* __restrict__ gw,
                                                const float* __restrict__ uw,
                                                u16* __restrict__ gwt,
                                                u16* __restrict__ uwt) {
  __shared__ float t[64][65];
  const int R = HH, C = II;
  int z = blockIdx.z;
  int e = z & 7;
  const float* in = (z < 8) ? gw : uw;
  u16* out = (z < 8) ? gwt : uwt;
  int r0 = blockIdx.y * 64, c0 = blockIdx.x * 64;
  const float* ip = in + (size_t)e * R * C;
  u16* op = out + (size_t)e * R * C;
  int tid = threadIdx.x;
  int rr = tid >> 4, c4 = (tid & 15) * 4;
#pragma unroll
  for (int j = 0; j < 4; ++j) {
    float4v v = *(const float4v*)&ip[(size_t)(r0 + rr + 16 * j) * C + c0 + c4];
    t[rr + 16 * j][c4 + 0] = v.x;
    t[rr + 16 * j][c4 + 1] = v.y;
    t[rr + 16 * j][c4 + 2] = v.z;
    t[rr + 16 * j][c4 + 3] = v.w;
  }
  __syncthreads();
  int cc = tid >> 2, rb = (tid & 3) * 16;
  u16 buf[16];
#pragma unroll
  for (int i = 0; i < 16; ++i) buf[i] = f2bf(t[rb + i][cc]);
  u16* p = op + (size_t)(c0 + cc) * R + r0 + rb;
  *(int4v*)p = *(const int4v*)&buf[0];
  *(int4v*)(p + 8) = *(const int4v*)&buf[8];
}

// ---------------- routing: gather rows by expert ----------------
__global__ __launch_bounds__(256) void k_route(const int* __restrict__ sel,
                                               const float* __restrict__ rw,
                                               int* __restrict__ token_idx,
                                               float* __restrict__ wrow,
                                               int* __restrict__ s_e,
                                               int* __restrict__ s_rs,
                                               int* __restrict__ s_rows) {
  __shared__ int cnt[NE], offs[NE + 1], cursor[NE];
  int tid = threadIdx.x;
  if (tid < NE) cnt[tid] = 0;
  __syncthreads();
  for (int i = tid; i < NROWS; i += 256) atomicAdd(&cnt[sel[i]], 1);
  __syncthreads();
  if (tid == 0) {
    int o = 0;
    for (int e = 0; e < NE; ++e) { offs[e] = o; o += cnt[e]; }
    offs[NE] = o;
    int ns = 0;
    for (int e = 0; e < NE; ++e) {
      for (int t = 0; t < cnt[e]; t += BM) {
        s_e[ns] = e;
        s_rs[ns] = offs[e] + t;
        s_rows[ns] = (cnt[e] - t < BM) ? (cnt[e] - t) : BM;
        ns++;
      }
    }
    for (; ns < MAX_SLOTS; ++ns) s_rows[ns] = 0;
  }
  __syncthreads();
  if (tid < NE) cursor[tid] = offs[tid];
  __syncthreads();
  for (int i = tid; i < NROWS; i += 256) {
    int e = sel[i];
    int r = atomicAdd(&cursor[e], 1);
    token_idx[r] = i >> 1;   // token id
    wrow[r] = rw[i];         // routing weight for this slot
  }
}

// ---------------- gate/up GEMM + SwiGLU epilogue (R10 body) ----------------
// m97 structure: single-buffered LDS, stage -> barrier -> MFMA -> barrier.
// 1D grid, XCD swizzle, YTILE-MAJOR within XCD: consecutive blocks share the
// same 0.5 MB weight panel (L2-resident across the XCD's 18 slots); A-tiles
// re-read per ytile pass hit L3 (hsb = 32 MB, L3-resident).
__global__ __launch_bounds__(256, 4) void k_gu(const u16* __restrict__ hsb,
                                               const u16* __restrict__ gwt,
                                               const u16* __restrict__ uwt,
                                               const int* __restrict__ token_idx,
                                               const float* __restrict__ wrow,
                                               const int* __restrict__ s_e,
                                               const int* __restrict__ s_rs,
                                               const int* __restrict__ s_rows,
                                               u16* __restrict__ act) {
  int f = blockIdx.x;
  int xcd = f & 7;
  int pos = f >> 3;                 // 0..395
  int slot = xcd * SPX + pos % SPX; // ytile-major: slot varies fastest
  int ytile = pos / SPX;
  int nrows = s_rows[slot];
  if (nrows == 0) return;
  int e = s_e[slot];
  int row0 = s_rs[slot];
  int i0 = ytile * 64;

  __shared__ alignas(16) u16 As[BM][BK];   // 16 KB
  __shared__ alignas(16) u16 Bg[64][BK];   // 8 KB
  __shared__ alignas(16) u16 Bu[64][BK];   // 8 KB  -> 32 KB total

  int tid = threadIdx.x;
  int lane = tid & 63;
  int wid = tid >> 6;
  int l8 = lane >> 3;
  int c8 = lane & 7;
  int cs = c8 ^ l8;            // swizzled source chunk (dest LDS linear, rule #21)

  const u16* agp[4];
#pragma unroll
  for (int j = 0; j < 4; ++j) {
    int gr = row0 + wid * 32 + j * 8 + l8;
    if (gr > NROWS - 1) gr = NROWS - 1;
    int tok = token_idx[gr];
    agp[j] = hsb + (size_t)tok * HH + cs * 8;
  }
  const u16* ggp[2]; const u16* ugp[2];
#pragma unroll
  for (int j = 0; j < 2; ++j) {
    size_t off = ((size_t)e * II + i0 + wid * 16 + j * 8 + l8) * HH + cs * 8;
    ggp[j] = gwt + off;
    ugp[j] = uwt + off;
  }

  int wm = wid >> 1, wn = wid & 1;
  int l15 = lane & 15, l16 = lane >> 4;

  f32x4 accg[4][2], accu[4][2];
#pragma unroll
  for (int a = 0; a < 4; ++a)
#pragma unroll
    for (int b = 0; b < 2; ++b) { accg[a][b] = (f32x4)0.0f; accu[a][b] = (f32x4)0.0f; }

  for (int kt = 0; kt < NKT_GU; ++kt) {
    int k0 = kt * BK;
#pragma unroll
    for (int j = 0; j < 4; ++j) gld16(agp[j] + k0, &As[wid * 32 + j * 8][0]);
#pragma unroll
    for (int j = 0; j < 2; ++j) {
      gld16(ggp[j] + k0, &Bg[wid * 16 + j * 8][0]);
      gld16(ugp[j] + k0, &Bu[wid * 16 + j * 8][0]);
    }
    __syncthreads();
#pragma unroll
    for (int ks = 0; ks < 2; ++ks) {
      bhalf8 af[4], bgf[2], buf_[2];
#pragma unroll
      for (int mf = 0; mf < 4; ++mf) {
        int row = wm * 64 + mf * 16 + l15;
        int c = (ks * 4 + l16) ^ (row & 7);
        af[mf] = *(const bhalf8*)&As[row][c * 8];
      }
#pragma unroll
      for (int nf = 0; nf < 2; ++nf) {
        int row = wn * 32 + nf * 16 + l15;
        int c = (ks * 4 + l16) ^ (row & 7);
        bgf[nf] = *(const bhalf8*)&Bg[row][c * 8];
        buf_[nf] = *(const bhalf8*)&Bu[row][c * 8];
      }
#pragma unroll
      for (int mf = 0; mf < 4; ++mf)
#pragma unroll
        for (int nf = 0; nf < 2; ++nf) {
          accg[mf][nf] = __builtin_amdgcn_mfma_f32_16x16x32_bf16(af[mf], bgf[nf], accg[mf][nf], 0, 0, 0);
          accu[mf][nf] = __builtin_amdgcn_mfma_f32_16x16x32_bf16(af[mf], buf_[nf], accu[mf][nf], 0, 0, 0);
        }
    }
    __syncthreads();
  }

  // epilogue: act = w * silu(g) * u
#pragma unroll
  for (int mf = 0; mf < 4; ++mf) {
#pragma unroll
    for (int j = 0; j < 4; ++j) {
      int lm = wm * 64 + mf * 16 + l16 * 4 + j;
      if (lm < nrows) {
        int gr = row0 + lm;
        float w = wrow[gr];
        size_t base = (size_t)gr * II + i0 + wn * 32 + l15;
#pragma unroll
        for (int nf = 0; nf < 2; ++nf) {
          float g = accg[mf][nf][j];
          float u = accu[mf][nf][j];
          float s = g / (1.0f + __expf(-g));
          act[base + nf * 16] = f2bf(s * u * w);
        }
      }
    }
  }
}

// ---------------- down GEMM (BN=128) + scatter-add, ytile-major ----------------
__global__ __launch_bounds__(256, 3) void k_down(const u16* __restrict__ act,
                                                 const u16* __restrict__ dwt,
                                                 const int* __restrict__ token_idx,
                                                 const int* __restrict__ s_e,
                                                 const int* __restrict__ s_rs,
                                                 const int* __restrict__ s_rows,
                                                 float* __restrict__ out) {
  int f = blockIdx.x;
  int xcd = f & 7;
  int pos = f >> 3;                 // 0..287
  int slot = xcd * SPX + pos % SPX; // ytile-major
  int ytile = pos / SPX;
  int nrows = s_rows[slot];
  if (nrows == 0) return;
  int e = s_e[slot];
  int row0 = s_rs[slot];
  int h0 = ytile * BND;

  __shared__ alignas(16) u16 As[BM][BK];    // 16 KB
  __shared__ alignas(16) u16 Bs[BND][BK];   // 16 KB -> 32 KB total

  int tid = threadIdx.x;
  int lane = tid & 63;
  int wid = tid >> 6;
  int l8 = lane >> 3;
  int c8 = lane & 7;
  int cs = c8 ^ l8;

  const u16* agp[4];
#pragma unroll
  for (int j = 0; j < 4; ++j) {
    int gr = row0 + wid * 32 + j * 8 + l8;
    if (gr > NROWS - 1) gr = NROWS - 1;
    agp[j] = act + (size_t)gr * II + cs * 8;
  }
  const u16* bgp[4];
#pragma unroll
  for (int j = 0; j < 4; ++j)
    bgp[j] = dwt + ((size_t)e * HH + h0 + wid * 32 + j * 8 + l8) * II + cs * 8;

  int wm = wid >> 1, wn = wid & 1;
  int l15 = lane & 15, l16 = lane >> 4;

  f32x4 acc[4][4];
#pragma unroll
  for (int a = 0; a < 4; ++a)
#pragma unroll
    for (int b = 0; b < 4; ++b) acc[a][b] = (f32x4)0.0f;

  for (int kt = 0; kt < NKT_DN; ++kt) {
    int k0 = kt * BK;
#pragma unroll
    for (int j = 0; j < 4; ++j) {
      gld16(agp[j] + k0, &As[wid * 32 + j * 8][0]);
      gld16(bgp[j] + k0, &Bs[wid * 32 + j * 8][0]);
    }
    __syncthreads();
#pragma unroll
    for (int ks = 0; ks < 2; ++ks) {
      bhalf8 af[4], bf[4];
#pragma unroll
      for (int mf = 0; mf < 4; ++mf) {
        int row = wm * 64 + mf * 16 + l15;
        int c = (ks * 4 + l16) ^ (row & 7);
        af[mf] = *(const bhalf8*)&As[row][c * 8];
      }
#pragma unroll
      for (int nf = 0; nf < 4; ++nf) {
        int row = wn * 64 + nf * 16 + l15;
        int c = (ks * 4 + l16) ^ (row & 7);
        bf[nf] = *(const bhalf8*)&Bs[row][c * 8];
      }
#pragma unroll
      for (int mf = 0; mf < 4; ++mf)
#pragma unroll
        for (int nf = 0; nf < 4; ++nf)
          acc[mf][nf] = __builtin_amdgcn_mfma_f32_16x16x32_bf16(af[mf], bf[nf], acc[mf][nf], 0, 0, 0);
    }
    __syncthreads();
  }

#pragma unroll
  for (int mf = 0; mf < 4; ++mf) {
#pragma unroll
    for (int j = 0; j < 4; ++j) {
      int lm = wm * 64 + mf * 16 + l16 * 4 + j;
      if (lm < nrows) {
        int tok = token_idx[row0 + lm];
        size_t base = (size_t)tok * HH + h0 + wn * 64 + l15;
#pragma unroll
        for (int nf = 0; nf < 4; ++nf)
          atomicAdd(&out[base + nf * 16], acc[mf][nf][j]);
      }
    }
  }
}

extern "C" void kernel_launch(void* const* d_in, const int* in_sizes, int n_in,
                              void* d_out, int out_size, void* d_ws, size_t ws_size,
                              hipStream_t stream) {
  const int* sel = (const int*)d_in[0];
  const float* hs = (const float*)d_in[1];
  const float* rw = (const float*)d_in[2];
  const float* gw = (const float*)d_in[3];
  const float* uw = (const float*)d_in[4];
  const float* dw = (const float*)d_in[5];
  float* out = (float*)d_out;

  char* ws = (char*)d_ws;
  size_t o = 0;
  u16* hsb = (u16*)(ws + o); o += (size_t)TT * HH * 2;           // 32 MB
  u16* gwt = (u16*)(ws + o); o += (size_t)NE * HH * II * 2;      // 44 MB
  u16* uwt = (u16*)(ws + o); o += (size_t)NE * HH * II * 2;      // 44 MB
  u16* dwt = (u16*)(ws + o); o += (size_t)NE * HH * II * 2;      // 44 MB
  u16* act = (u16*)(ws + o); o += (size_t)NROWS * II * 2;        // 44 MB
  int* token_idx = (int*)(ws + o); o += (size_t)NROWS * 4;
  float* wrow = (float*)(ws + o); o += (size_t)NROWS * 4;
  int* s_e = (int*)(ws + o); o += MAX_SLOTS * 4;
  int* s_rs = (int*)(ws + o); o += MAX_SLOTS * 4;
  int* s_rows = (int*)(ws + o); o += MAX_SLOTS * 4;
  (void)ws_size; (void)in_sizes; (void)n_in; (void)out_size;

  // fp32 -> bf16 conversions (+ weight transpose to [N][K])
  k_cvt_hs<<<(TT * HH) / 2048, 256, 0, stream>>>(hs, hsb);
  dim3 g1(II / 64, HH / 64, 2 * NE);
  k_tconv2<<<g1, 256, 0, stream>>>(gw, uw, gwt, uwt);
  dim3 g2(HH / 64, II / 64, NE);
  k_tconv<<<g2, 256, 0, stream>>>(dw, dwt, II, HH);

  // routing + zero output
  k_route<<<1, 256, 0, stream>>>(sel, rw, token_idx, wrow, s_e, s_rs, s_rows);
  hipMemsetAsync(d_out, 0, (size_t)TT * HH * 4, stream);

  // gate/up GEMM + SwiGLU  (1D grid, XCD swizzle, ytile-major)
  k_gu<<<MAX_SLOTS * NYT_GU, 256, 0, stream>>>(hsb, gwt, uwt, token_idx, wrow,
                                               s_e, s_rs, s_rows, act);

  // down GEMM with scatter-add  (1D grid, XCD swizzle, ytile-major)
  k_down<<<MAX_SLOTS * NYT_DN, 256, 0, stream>>>(act, dwt, token_idx,
                                                 s_e, s_rs, s_rows, out);
}

// Round 13
// 538.692 us; speedup vs baseline: 5.9975x; 1.0465x over previous
//
#include <hip/hip_runtime.h>
#include <stdint.h>

// Problem constants (fixed shapes)
#define TT 8192      // tokens = B*S
#define HH 2048      // hidden dim
#define II 1408      // intermediate dim
#define NE 8         // experts
#define NROWS (TT*2) // (token, slot) rows = 16384
#define BM 128       // row tile
#define BK 64        // k tile
#define BND 128      // k_down N tile
#define MAX_SLOTS 144
#define NKT_GU (HH/BK)   // 32
#define NKT_DN (II/BK)   // 22
#define NYT_GU (II/64)   // 22  N-tiles in k_gu (N=64 per B-matrix, gate+up)
#define NYT_DN (HH/BND)  // 16  N-tiles in k_down
#define SPX (MAX_SLOTS/8)  // 18 slots per XCD

// k_prep block ranges
#define NB_CVT 8192                  // (TT*HH)/2048
#define NB_T2  (22*32*16)            // 11264 gate+up transpose
#define NB_TD  (32*22*8)             // 5632  down transpose
#define NB_Z   2048                  // output zeroing
#define B0_CVT 1
#define B0_T2  (B0_CVT + NB_CVT)     // 8193
#define B0_TD  (B0_T2 + NB_T2)       // 19457
#define B0_Z   (B0_TD + NB_TD)       // 25089
#define NB_ALL (B0_Z + NB_Z)         // 27137

typedef unsigned short u16;
typedef __attribute__((ext_vector_type(8))) __bf16 bhalf8;
typedef __attribute__((ext_vector_type(4))) float f32x4;
typedef __attribute__((ext_vector_type(4))) float float4v;
typedef __attribute__((ext_vector_type(4))) int int4v;

__device__ __forceinline__ u16 f2bf(float f) {
  union { float f; unsigned u; } v; v.f = f;
  return (u16)((v.u + 0x7FFFu + ((v.u >> 16) & 1u)) >> 16);  // RNE
}

__device__ __forceinline__ void gld16(const void* g, void* l) {
  __builtin_amdgcn_global_load_lds(
      (const __attribute__((address_space(1))) unsigned int*)g,
      (__attribute__((address_space(3))) unsigned int*)l, 16, 0, 0);
}

// ---------------- fused preprocessing ----------------
// block 0: routing; [B0_CVT,B0_T2): hs fp32->bf16; [B0_T2,B0_TD): gate/up
// transpose+cvt; [B0_TD,B0_Z): down transpose+cvt; [B0_Z,NB_ALL): zero out.
__global__ __launch_bounds__(256) void k_prep(const int* __restrict__ sel,
                                              const float* __restrict__ rw,
                                              const float* __restrict__ hs,
                                              const float* __restrict__ gw,
                                              const float* __restrict__ uw,
                                              const float* __restrict__ dw,
                                              u16* __restrict__ hsb,
                                              u16* __restrict__ gwt,
                                              u16* __restrict__ uwt,
                                              u16* __restrict__ dwt,
                                              float* __restrict__ outz,
                                              int* __restrict__ token_idx,
                                              float* __restrict__ wrow,
                                              int* __restrict__ s_e,
                                              int* __restrict__ s_rs,
                                              int* __restrict__ s_rows) {
  int b = blockIdx.x;
  int tid = threadIdx.x;

  if (b == 0) {
    // ---- routing (single block) ----
    __shared__ int cnt[NE], offs[NE + 1], cursor[NE];
    if (tid < NE) cnt[tid] = 0;
    __syncthreads();
    for (int i = tid; i < NROWS; i += 256) atomicAdd(&cnt[sel[i]], 1);
    __syncthreads();
    if (tid == 0) {
      int o = 0;
      for (int e = 0; e < NE; ++e) { offs[e] = o; o += cnt[e]; }
      offs[NE] = o;
      int ns = 0;
      for (int e = 0; e < NE; ++e) {
        for (int t = 0; t < cnt[e]; t += BM) {
          s_e[ns] = e;
          s_rs[ns] = offs[e] + t;
          s_rows[ns] = (cnt[e] - t < BM) ? (cnt[e] - t) : BM;
          ns++;
        }
      }
      for (; ns < MAX_SLOTS; ++ns) s_rows[ns] = 0;
    }
    __syncthreads();
    if (tid < NE) cursor[tid] = offs[tid];
    __syncthreads();
    for (int i = tid; i < NROWS; i += 256) {
      int e = sel[i];
      int r = atomicAdd(&cursor[e], 1);
      token_idx[r] = i >> 1;
      wrow[r] = rw[i];
    }
    return;
  }

  if (b < B0_T2) {
    // ---- hs fp32 -> bf16 ----
    size_t i = ((size_t)(b - B0_CVT) * 256 + tid) * 8;
    float4v a = *(const float4v*)(hs + i);
    float4v c = *(const float4v*)(hs + i + 4);
    u16 o[8];
    o[0] = f2bf(a.x); o[1] = f2bf(a.y); o[2] = f2bf(a.z); o[3] = f2bf(a.w);
    o[4] = f2bf(c.x); o[5] = f2bf(c.y); o[6] = f2bf(c.z); o[7] = f2bf(c.w);
    *(int4v*)(hsb + i) = *(const int4v*)o;
    return;
  }

  if (b >= B0_Z) {
    // ---- zero output (grid-stride int4) ----
    int4v z = (int4v)0;
    size_t n4 = (size_t)TT * HH / 4;
    for (size_t i = (size_t)(b - B0_Z) * 256 + tid; i < n4; i += (size_t)NB_Z * 256)
      ((int4v*)outz)[i] = z;
    return;
  }

  // ---- weight transpose + cvt roles (shared LDS tile) ----
  __shared__ float t[64][65];
  const float* ip;
  u16* op;
  int R, C, r0, c0;
  if (b < B0_TD) {
    // gate/up: dims x=II/64=22, y=HH/64=32, z=16 (z&7=expert, z>=8 -> up)
    int idx = b - B0_T2;
    int x = idx % 22, y = (idx / 22) % 32, z = idx / (22 * 32);
    int e = z & 7;
    R = HH; C = II;
    ip = ((z < 8) ? gw : uw) + (size_t)e * R * C;
    op = ((z < 8) ? gwt : uwt) + (size_t)e * R * C;
    r0 = y * 64; c0 = x * 64;
  } else {
    // down: dims x=HH/64=32, y=II/64=22, z=8
    int idx = b - B0_TD;
    int x = idx % 32, y = (idx / 32) % 22, z = idx / (32 * 22);
    R = II; C = HH;
    ip = dw + (size_t)z * R * C;
    op = dwt + (size_t)z * R * C;
    r0 = y * 64; c0 = x * 64;
  }
  int rr = tid >> 4, c4 = (tid & 15) * 4;
#pragma unroll
  for (int j = 0; j < 4; ++j) {
    float4v v = *(const float4v*)&ip[(size_t)(r0 + rr + 16 * j) * C + c0 + c4];
    t[rr + 16 * j][c4 + 0] = v.x;
    t[rr + 16 * j][c4 + 1] = v.y;
    t[rr + 16 * j][c4 + 2] = v.z;
    t[rr + 16 * j][c4 + 3] = v.w;
  }
  __syncthreads();
  int cc = tid >> 2, rb = (tid & 3) * 16;
  u16 buf[16];
#pragma unroll
  for (int i = 0; i < 16; ++i) buf[i] = f2bf(t[rb + i][cc]);
  u16* p = op + (size_t)(c0 + cc) * R + r0 + rb;
  *(int4v*)p = *(const int4v*)&buf[0];
  *(int4v*)(p + 8) = *(const int4v*)&buf[8];
}

// ---------------- gate/up GEMM + SwiGLU epilogue (R12 verbatim) ----------------
__global__ __launch_bounds__(256, 4) void k_gu(const u16* __restrict__ hsb,
                                               const u16* __restrict__ gwt,
                                               const u16* __restrict__ uwt,
                                               const int* __restrict__ token_idx,
                                               const float* __restrict__ wrow,
                                               const int* __restrict__ s_e,
                                               const int* __restrict__ s_rs,
                                               const int* __restrict__ s_rows,
                                               u16* __restrict__ act) {
  int f = blockIdx.x;
  int xcd = f & 7;
  int pos = f >> 3;                 // 0..395
  int slot = xcd * SPX + pos % SPX; // ytile-major
  int ytile = pos / SPX;
  int nrows = s_rows[slot];
  if (nrows == 0) return;
  int e = s_e[slot];
  int row0 = s_rs[slot];
  int i0 = ytile * 64;

  __shared__ alignas(16) u16 As[BM][BK];   // 16 KB
  __shared__ alignas(16) u16 Bg[64][BK];   // 8 KB
  __shared__ alignas(16) u16 Bu[64][BK];   // 8 KB  -> 32 KB total

  int tid = threadIdx.x;
  int lane = tid & 63;
  int wid = tid >> 6;
  int l8 = lane >> 3;
  int c8 = lane & 7;
  int cs = c8 ^ l8;            // swizzled source chunk (dest LDS linear, rule #21)

  const u16* agp[4];
#pragma unroll
  for (int j = 0; j < 4; ++j) {
    int gr = row0 + wid * 32 + j * 8 + l8;
    if (gr > NROWS - 1) gr = NROWS - 1;
    int tok = token_idx[gr];
    agp[j] = hsb + (size_t)tok * HH + cs * 8;
  }
  const u16* ggp[2]; const u16* ugp[2];
#pragma unroll
  for (int j = 0; j < 2; ++j) {
    size_t off = ((size_t)e * II + i0 + wid * 16 + j * 8 + l8) * HH + cs * 8;
    ggp[j] = gwt + off;
    ugp[j] = uwt + off;
  }

  int wm = wid >> 1, wn = wid & 1;
  int l15 = lane & 15, l16 = lane >> 4;

  f32x4 accg[4][2], accu[4][2];
#pragma unroll
  for (int a = 0; a < 4; ++a)
#pragma unroll
    for (int b = 0; b < 2; ++b) { accg[a][b] = (f32x4)0.0f; accu[a][b] = (f32x4)0.0f; }

  for (int kt = 0; kt < NKT_GU; ++kt) {
    int k0 = kt * BK;
#pragma unroll
    for (int j = 0; j < 4; ++j) gld16(agp[j] + k0, &As[wid * 32 + j * 8][0]);
#pragma unroll
    for (int j = 0; j < 2; ++j) {
      gld16(ggp[j] + k0, &Bg[wid * 16 + j * 8][0]);
      gld16(ugp[j] + k0, &Bu[wid * 16 + j * 8][0]);
    }
    __syncthreads();
#pragma unroll
    for (int ks = 0; ks < 2; ++ks) {
      bhalf8 af[4], bgf[2], buf_[2];
#pragma unroll
      for (int mf = 0; mf < 4; ++mf) {
        int row = wm * 64 + mf * 16 + l15;
        int c = (ks * 4 + l16) ^ (row & 7);
        af[mf] = *(const bhalf8*)&As[row][c * 8];
      }
#pragma unroll
      for (int nf = 0; nf < 2; ++nf) {
        int row = wn * 32 + nf * 16 + l15;
        int c = (ks * 4 + l16) ^ (row & 7);
        bgf[nf] = *(const bhalf8*)&Bg[row][c * 8];
        buf_[nf] = *(const bhalf8*)&Bu[row][c * 8];
      }
#pragma unroll
      for (int mf = 0; mf < 4; ++mf)
#pragma unroll
        for (int nf = 0; nf < 2; ++nf) {
          accg[mf][nf] = __builtin_amdgcn_mfma_f32_16x16x32_bf16(af[mf], bgf[nf], accg[mf][nf], 0, 0, 0);
          accu[mf][nf] = __builtin_amdgcn_mfma_f32_16x16x32_bf16(af[mf], buf_[nf], accu[mf][nf], 0, 0, 0);
        }
    }
    __syncthreads();
  }

  // epilogue: act = w * silu(g) * u
#pragma unroll
  for (int mf = 0; mf < 4; ++mf) {
#pragma unroll
    for (int j = 0; j < 4; ++j) {
      int lm = wm * 64 + mf * 16 + l16 * 4 + j;
      if (lm < nrows) {
        int gr = row0 + lm;
        float w = wrow[gr];
        size_t base = (size_t)gr * II + i0 + wn * 32 + l15;
#pragma unroll
        for (int nf = 0; nf < 2; ++nf) {
          float g = accg[mf][nf][j];
          float u = accu[mf][nf][j];
          float s = g / (1.0f + __expf(-g));
          act[base + nf * 16] = f2bf(s * u * w);
        }
      }
    }
  }
}

// ---------------- down GEMM (BN=128) + scatter-add (R12 verbatim) --------------
__global__ __launch_bounds__(256, 3) void k_down(const u16* __restrict__ act,
                                                 const u16* __restrict__ dwt,
                                                 const int* __restrict__ token_idx,
                                                 const int* __restrict__ s_e,
                                                 const int* __restrict__ s_rs,
                                                 const int* __restrict__ s_rows,
                                                 float* __restrict__ out) {
  int f = blockIdx.x;
  int xcd = f & 7;
  int pos = f >> 3;                 // 0..287
  int slot = xcd * SPX + pos % SPX; // ytile-major
  int ytile = pos / SPX;
  int nrows = s_rows[slot];
  if (nrows == 0) return;
  int e = s_e[slot];
  int row0 = s_rs[slot];
  int h0 = ytile * BND;

  __shared__ alignas(16) u16 As[BM][BK];    // 16 KB
  __shared__ alignas(16) u16 Bs[BND][BK];   // 16 KB -> 32 KB total

  int tid = threadIdx.x;
  int lane = tid & 63;
  int wid = tid >> 6;
  int l8 = lane >> 3;
  int c8 = lane & 7;
  int cs = c8 ^ l8;

  const u16* agp[4];
#pragma unroll
  for (int j = 0; j < 4; ++j) {
    int gr = row0 + wid * 32 + j * 8 + l8;
    if (gr > NROWS - 1) gr = NROWS - 1;
    agp[j] = act + (size_t)gr * II + cs * 8;
  }
  const u16* bgp[4];
#pragma unroll
  for (int j = 0; j < 4; ++j)
    bgp[j] = dwt + ((size_t)e * HH + h0 + wid * 32 + j * 8 + l8) * II + cs * 8;

  int wm = wid >> 1, wn = wid & 1;
  int l15 = lane & 15, l16 = lane >> 4;

  f32x4 acc[4][4];
#pragma unroll
  for (int a = 0; a < 4; ++a)
#pragma unroll
    for (int b = 0; b < 4; ++b) acc[a][b] = (f32x4)0.0f;

  for (int kt = 0; kt < NKT_DN; ++kt) {
    int k0 = kt * BK;
#pragma unroll
    for (int j = 0; j < 4; ++j) {
      gld16(agp[j] + k0, &As[wid * 32 + j * 8][0]);
      gld16(bgp[j] + k0, &Bs[wid * 32 + j * 8][0]);
    }
    __syncthreads();
#pragma unroll
    for (int ks = 0; ks < 2; ++ks) {
      bhalf8 af[4], bf[4];
#pragma unroll
      for (int mf = 0; mf < 4; ++mf) {
        int row = wm * 64 + mf * 16 + l15;
        int c = (ks * 4 + l16) ^ (row & 7);
        af[mf] = *(const bhalf8*)&As[row][c * 8];
      }
#pragma unroll
      for (int nf = 0; nf < 4; ++nf) {
        int row = wn * 64 + nf * 16 + l15;
        int c = (ks * 4 + l16) ^ (row & 7);
        bf[nf] = *(const bhalf8*)&Bs[row][c * 8];
      }
#pragma unroll
      for (int mf = 0; mf < 4; ++mf)
#pragma unroll
        for (int nf = 0; nf < 4; ++nf)
          acc[mf][nf] = __builtin_amdgcn_mfma_f32_16x16x32_bf16(af[mf], bf[nf], acc[mf][nf], 0, 0, 0);
    }
    __syncthreads();
  }

#pragma unroll
  for (int mf = 0; mf < 4; ++mf) {
#pragma unroll
    for (int j = 0; j < 4; ++j) {
      int lm = wm * 64 + mf * 16 + l16 * 4 + j;
      if (lm < nrows) {
        int tok = token_idx[row0 + lm];
        size_t base = (size_t)tok * HH + h0 + wn * 64 + l15;
#pragma unroll
        for (int nf = 0; nf < 4; ++nf)
          atomicAdd(&out[base + nf * 16], acc[mf][nf][j]);
      }
    }
  }
}

extern "C" void kernel_launch(void* const* d_in, const int* in_sizes, int n_in,
                              void* d_out, int out_size, void* d_ws, size_t ws_size,
                              hipStream_t stream) {
  const int* sel = (const int*)d_in[0];
  const float* hs = (const float*)d_in[1];
  const float* rw = (const float*)d_in[2];
  const float* gw = (const float*)d_in[3];
  const float* uw = (const float*)d_in[4];
  const float* dw = (const float*)d_in[5];
  float* out = (float*)d_out;

  char* ws = (char*)d_ws;
  size_t o = 0;
  u16* hsb = (u16*)(ws + o); o += (size_t)TT * HH * 2;           // 32 MB
  u16* gwt = (u16*)(ws + o); o += (size_t)NE * HH * II * 2;      // 44 MB
  u16* uwt = (u16*)(ws + o); o += (size_t)NE * HH * II * 2;      // 44 MB
  u16* dwt = (u16*)(ws + o); o += (size_t)NE * HH * II * 2;      // 44 MB
  u16* act = (u16*)(ws + o); o += (size_t)NROWS * II * 2;        // 44 MB
  int* token_idx = (int*)(ws + o); o += (size_t)NROWS * 4;
  float* wrow = (float*)(ws + o); o += (size_t)NROWS * 4;
  int* s_e = (int*)(ws + o); o += MAX_SLOTS * 4;
  int* s_rs = (int*)(ws + o); o += MAX_SLOTS * 4;
  int* s_rows = (int*)(ws + o); o += MAX_SLOTS * 4;
  (void)ws_size; (void)in_sizes; (void)n_in; (void)out_size;

  // fused preprocessing: routing + conversions + transposes + output zeroing
  k_prep<<<NB_ALL, 256, 0, stream>>>(sel, rw, hs, gw, uw, dw,
                                     hsb, gwt, uwt, dwt, out,
                                     token_idx, wrow, s_e, s_rs, s_rows);

  // gate/up GEMM + SwiGLU  (1D grid, XCD swizzle, ytile-major)
  k_gu<<<MAX_SLOTS * NYT_GU, 256, 0, stream>>>(hsb, gwt, uwt, token_idx, wrow,
                                               s_e, s_rs, s_rows, act);

  // down GEMM with scatter-add  (1D grid, XCD swizzle, ytile-major)
  k_down<<<MAX_SLOTS * NYT_DN, 256, 0, stream>>>(act, dwt, token_idx,
                                                 s_e, s_rs, s_rows, out);
}

// Round 14
// 530.894 us; speedup vs baseline: 6.0856x; 1.0147x over previous
//
#include <hip/hip_runtime.h>
#include <stdint.h>

// Problem constants (fixed shapes)
#define TT 8192      // tokens = B*S
#define HH 2048      // hidden dim
#define II 1408      // intermediate dim
#define NE 8         // experts
#define NROWS (TT*2) // (token, slot) rows = 16384
#define BM 128       // row tile
#define BK 64        // k tile
#define BND 128      // k_down N tile
#define MAX_SLOTS 144
#define NKT_GU (HH/BK)   // 32
#define NKT_DN (II/BK)   // 22
#define NYT_GU (II/64)   // 22  N-tiles in k_gu
#define NYT_DN (HH/BND)  // 16  N-tiles in k_down
#define SPX (MAX_SLOTS/8)  // 18 slots per XCD

// k_prep block ranges: routing + hs cvt + gate/up transpose only
#define NB_CVT 8192                  // (TT*HH)/2048
#define NB_T2  (22*32*16)            // 11264 gate+up transpose
#define B0_CVT 1
#define B0_T2  (B0_CVT + NB_CVT)     // 8193
#define NB_PREP (B0_T2 + NB_T2)      // 19457

// k_gu tail blocks: down transpose + output zeroing (needed only by k_down)
#define NBG (MAX_SLOTS*NYT_GU)       // 3168 GEMM blocks
#define NB_TD (32*22*8)              // 5632 down transpose
#define NB_Z  512                    // zero blocks (grid-stride)
#define NBG_ALL (NBG + NB_TD + NB_Z) // 9312

typedef unsigned short u16;
typedef __attribute__((ext_vector_type(8))) __bf16 bhalf8;
typedef __attribute__((ext_vector_type(4))) float f32x4;
typedef __attribute__((ext_vector_type(4))) float float4v;
typedef __attribute__((ext_vector_type(4))) int int4v;

__device__ __forceinline__ u16 f2bf(float f) {
  union { float f; unsigned u; } v; v.f = f;
  return (u16)((v.u + 0x7FFFu + ((v.u >> 16) & 1u)) >> 16);  // RNE
}

__device__ __forceinline__ void gld16(const void* g, void* l) {
  __builtin_amdgcn_global_load_lds(
      (const __attribute__((address_space(1))) unsigned int*)g,
      (__attribute__((address_space(3))) unsigned int*)l, 16, 0, 0);
}

// ---------------- preprocessing: route + hs cvt + gate/up transpose ------------
__global__ __launch_bounds__(256) void k_prep(const int* __restrict__ sel,
                                              const float* __restrict__ rw,
                                              const float* __restrict__ hs,
                                              const float* __restrict__ gw,
                                              const float* __restrict__ uw,
                                              u16* __restrict__ hsb,
                                              u16* __restrict__ gwt,
                                              u16* __restrict__ uwt,
                                              int* __restrict__ token_idx,
                                              float* __restrict__ wrow,
                                              int* __restrict__ s_e,
                                              int* __restrict__ s_rs,
                                              int* __restrict__ s_rows) {
  int b = blockIdx.x;
  int tid = threadIdx.x;

  if (b == 0) {
    __shared__ int cnt[NE], offs[NE + 1], cursor[NE];
    if (tid < NE) cnt[tid] = 0;
    __syncthreads();
    for (int i = tid; i < NROWS; i += 256) atomicAdd(&cnt[sel[i]], 1);
    __syncthreads();
    if (tid == 0) {
      int o = 0;
      for (int e = 0; e < NE; ++e) { offs[e] = o; o += cnt[e]; }
      offs[NE] = o;
      int ns = 0;
      for (int e = 0; e < NE; ++e) {
        for (int t = 0; t < cnt[e]; t += BM) {
          s_e[ns] = e;
          s_rs[ns] = offs[e] + t;
          s_rows[ns] = (cnt[e] - t < BM) ? (cnt[e] - t) : BM;
          ns++;
        }
      }
      for (; ns < MAX_SLOTS; ++ns) s_rows[ns] = 0;
    }
    __syncthreads();
    if (tid < NE) cursor[tid] = offs[tid];
    __syncthreads();
    for (int i = tid; i < NROWS; i += 256) {
      int e = sel[i];
      int r = atomicAdd(&cursor[e], 1);
      token_idx[r] = i >> 1;
      wrow[r] = rw[i];
    }
    return;
  }

  if (b < B0_T2) {
    size_t i = ((size_t)(b - B0_CVT) * 256 + tid) * 8;
    float4v a = *(const float4v*)(hs + i);
    float4v c = *(const float4v*)(hs + i + 4);
    u16 o[8];
    o[0] = f2bf(a.x); o[1] = f2bf(a.y); o[2] = f2bf(a.z); o[3] = f2bf(a.w);
    o[4] = f2bf(c.x); o[5] = f2bf(c.y); o[6] = f2bf(c.z); o[7] = f2bf(c.w);
    *(int4v*)(hsb + i) = *(const int4v*)o;
    return;
  }

  // gate/up transpose+cvt: x=II/64=22, y=HH/64=32, z=16
  __shared__ float t[64][65];
  int idx = b - B0_T2;
  int x = idx % 22, y = (idx / 22) % 32, z = idx / (22 * 32);
  int e = z & 7;
  const int R = HH, C = II;
  const float* ip = ((z < 8) ? gw : uw) + (size_t)e * R * C;
  u16* op = ((z < 8) ? gwt : uwt) + (size_t)e * R * C;
  int r0 = y * 64, c0 = x * 64;
  int rr = tid >> 4, c4 = (tid & 15) * 4;
#pragma unroll
  for (int j = 0; j < 4; ++j) {
    float4v v = *(const float4v*)&ip[(size_t)(r0 + rr + 16 * j) * C + c0 + c4];
    t[rr + 16 * j][c4 + 0] = v.x;
    t[rr + 16 * j][c4 + 1] = v.y;
    t[rr + 16 * j][c4 + 2] = v.z;
    t[rr + 16 * j][c4 + 3] = v.w;
  }
  __syncthreads();
  int cc = tid >> 2, rb = (tid & 3) * 16;
  u16 buf[16];
#pragma unroll
  for (int i = 0; i < 16; ++i) buf[i] = f2bf(t[rb + i][cc]);
  u16* p = op + (size_t)(c0 + cc) * R + r0 + rb;
  *(int4v*)p = *(const int4v*)&buf[0];
  *(int4v*)(p + 8) = *(const int4v*)&buf[8];
}

// ---------------- gate/up GEMM + SwiGLU, with tail blocks ----------------
// Blocks [0,NBG): R13 GEMM (m97 structure, XCD swizzle, ytile-major).
// Blocks [NBG,NBG+NB_TD): down-weight transpose (needed only by k_down).
// Blocks [NBG+NB_TD,NBG_ALL): zero d_out. Tail blocks dispatch last and fill
// CU holes during the GEMM drain. LDS unioned via one 32 KB buffer.
__global__ __launch_bounds__(256, 4) void k_gu(const u16* __restrict__ hsb,
                                               const u16* __restrict__ gwt,
                                               const u16* __restrict__ uwt,
                                               const int* __restrict__ token_idx,
                                               const float* __restrict__ wrow,
                                               const int* __restrict__ s_e,
                                               const int* __restrict__ s_rs,
                                               const int* __restrict__ s_rows,
                                               u16* __restrict__ act,
                                               const float* __restrict__ dw,
                                               u16* __restrict__ dwt,
                                               float* __restrict__ outz) {
  __shared__ alignas(16) char smem[32768];
  int f = blockIdx.x;
  int tid = threadIdx.x;

  if (f >= NBG) {
    int b = f - NBG;
    if (b < NB_TD) {
      // ---- down transpose+cvt: x=HH/64=32, y=II/64=22, z=8 ----
      float (*t)[65] = (float(*)[65])smem;   // 16.6 KB of the union
      int x = b % 32, y = (b / 32) % 22, z = b / (32 * 22);
      const int R = II, C = HH;
      const float* ip = dw + (size_t)z * R * C;
      u16* op = dwt + (size_t)z * R * C;
      int r0 = y * 64, c0 = x * 64;
      int rr = tid >> 4, c4 = (tid & 15) * 4;
#pragma unroll
      for (int j = 0; j < 4; ++j) {
        float4v v = *(const float4v*)&ip[(size_t)(r0 + rr + 16 * j) * C + c0 + c4];
        t[rr + 16 * j][c4 + 0] = v.x;
        t[rr + 16 * j][c4 + 1] = v.y;
        t[rr + 16 * j][c4 + 2] = v.z;
        t[rr + 16 * j][c4 + 3] = v.w;
      }
      __syncthreads();
      int cc = tid >> 2, rb = (tid & 3) * 16;
      u16 buf[16];
#pragma unroll
      for (int i = 0; i < 16; ++i) buf[i] = f2bf(t[rb + i][cc]);
      u16* p = op + (size_t)(c0 + cc) * R + r0 + rb;
      *(int4v*)p = *(const int4v*)&buf[0];
      *(int4v*)(p + 8) = *(const int4v*)&buf[8];
    } else {
      // ---- zero d_out (grid-stride int4) ----
      int4v zv = (int4v)0;
      size_t n4 = (size_t)TT * HH / 4;
      for (size_t i = (size_t)(b - NB_TD) * 256 + tid; i < n4;
           i += (size_t)NB_Z * 256)
        ((int4v*)outz)[i] = zv;
    }
    return;
  }

  // ---- GEMM path (R13 verbatim, LDS via union) ----
  u16 (*As)[BK] = (u16(*)[BK])(smem);           // 16 KB
  u16 (*Bg)[BK] = (u16(*)[BK])(smem + 16384);   // 8 KB
  u16 (*Bu)[BK] = (u16(*)[BK])(smem + 24576);   // 8 KB

  int xcd = f & 7;
  int pos = f >> 3;                 // 0..395
  int slot = xcd * SPX + pos % SPX; // ytile-major
  int ytile = pos / SPX;
  int nrows = s_rows[slot];
  if (nrows == 0) return;
  int e = s_e[slot];
  int row0 = s_rs[slot];
  int i0 = ytile * 64;

  int lane = tid & 63;
  int wid = tid >> 6;
  int l8 = lane >> 3;
  int c8 = lane & 7;
  int cs = c8 ^ l8;            // swizzled source chunk (dest LDS linear, rule #21)

  const u16* agp[4];
#pragma unroll
  for (int j = 0; j < 4; ++j) {
    int gr = row0 + wid * 32 + j * 8 + l8;
    if (gr > NROWS - 1) gr = NROWS - 1;
    int tok = token_idx[gr];
    agp[j] = hsb + (size_t)tok * HH + cs * 8;
  }
  const u16* ggp[2]; const u16* ugp[2];
#pragma unroll
  for (int j = 0; j < 2; ++j) {
    size_t off = ((size_t)e * II + i0 + wid * 16 + j * 8 + l8) * HH + cs * 8;
    ggp[j] = gwt + off;
    ugp[j] = uwt + off;
  }

  int wm = wid >> 1, wn = wid & 1;
  int l15 = lane & 15, l16 = lane >> 4;

  f32x4 accg[4][2], accu[4][2];
#pragma unroll
  for (int a = 0; a < 4; ++a)
#pragma unroll
    for (int b2 = 0; b2 < 2; ++b2) { accg[a][b2] = (f32x4)0.0f; accu[a][b2] = (f32x4)0.0f; }

  for (int kt = 0; kt < NKT_GU; ++kt) {
    int k0 = kt * BK;
#pragma unroll
    for (int j = 0; j < 4; ++j) gld16(agp[j] + k0, &As[wid * 32 + j * 8][0]);
#pragma unroll
    for (int j = 0; j < 2; ++j) {
      gld16(ggp[j] + k0, &Bg[wid * 16 + j * 8][0]);
      gld16(ugp[j] + k0, &Bu[wid * 16 + j * 8][0]);
    }
    __syncthreads();
#pragma unroll
    for (int ks = 0; ks < 2; ++ks) {
      bhalf8 af[4], bgf[2], buf_[2];
#pragma unroll
      for (int mf = 0; mf < 4; ++mf) {
        int row = wm * 64 + mf * 16 + l15;
        int c = (ks * 4 + l16) ^ (row & 7);
        af[mf] = *(const bhalf8*)&As[row][c * 8];
      }
#pragma unroll
      for (int nf = 0; nf < 2; ++nf) {
        int row = wn * 32 + nf * 16 + l15;
        int c = (ks * 4 + l16) ^ (row & 7);
        bgf[nf] = *(const bhalf8*)&Bg[row][c * 8];
        buf_[nf] = *(const bhalf8*)&Bu[row][c * 8];
      }
#pragma unroll
      for (int mf = 0; mf < 4; ++mf)
#pragma unroll
        for (int nf = 0; nf < 2; ++nf) {
          accg[mf][nf] = __builtin_amdgcn_mfma_f32_16x16x32_bf16(af[mf], bgf[nf], accg[mf][nf], 0, 0, 0);
          accu[mf][nf] = __builtin_amdgcn_mfma_f32_16x16x32_bf16(af[mf], buf_[nf], accu[mf][nf], 0, 0, 0);
        }
    }
    __syncthreads();
  }

  // epilogue: act = w * silu(g) * u
#pragma unroll
  for (int mf = 0; mf < 4; ++mf) {
#pragma unroll
    for (int j = 0; j < 4; ++j) {
      int lm = wm * 64 + mf * 16 + l16 * 4 + j;
      if (lm < nrows) {
        int gr = row0 + lm;
        float w = wrow[gr];
        size_t base = (size_t)gr * II + i0 + wn * 32 + l15;
#pragma unroll
        for (int nf = 0; nf < 2; ++nf) {
          float g = accg[mf][nf][j];
          float u = accu[mf][nf][j];
          float s = g / (1.0f + __expf(-g));
          act[base + nf * 16] = f2bf(s * u * w);
        }
      }
    }
  }
}

// ---------------- down GEMM (BN=128) + scatter-add (R13 verbatim) --------------
__global__ __launch_bounds__(256, 3) void k_down(const u16* __restrict__ act,
                                                 const u16* __restrict__ dwt,
                                                 const int* __restrict__ token_idx,
                                                 const int* __restrict__ s_e,
                                                 const int* __restrict__ s_rs,
                                                 const int* __restrict__ s_rows,
                                                 float* __restrict__ out) {
  int f = blockIdx.x;
  int xcd = f & 7;
  int pos = f >> 3;                 // 0..287
  int slot = xcd * SPX + pos % SPX; // ytile-major
  int ytile = pos / SPX;
  int nrows = s_rows[slot];
  if (nrows == 0) return;
  int e = s_e[slot];
  int row0 = s_rs[slot];
  int h0 = ytile * BND;

  __shared__ alignas(16) u16 As[BM][BK];    // 16 KB
  __shared__ alignas(16) u16 Bs[BND][BK];   // 16 KB -> 32 KB total

  int tid = threadIdx.x;
  int lane = tid & 63;
  int wid = tid >> 6;
  int l8 = lane >> 3;
  int c8 = lane & 7;
  int cs = c8 ^ l8;

  const u16* agp[4];
#pragma unroll
  for (int j = 0; j < 4; ++j) {
    int gr = row0 + wid * 32 + j * 8 + l8;
    if (gr > NROWS - 1) gr = NROWS - 1;
    agp[j] = act + (size_t)gr * II + cs * 8;
  }
  const u16* bgp[4];
#pragma unroll
  for (int j = 0; j < 4; ++j)
    bgp[j] = dwt + ((size_t)e * HH + h0 + wid * 32 + j * 8 + l8) * II + cs * 8;

  int wm = wid >> 1, wn = wid & 1;
  int l15 = lane & 15, l16 = lane >> 4;

  f32x4 acc[4][4];
#pragma unroll
  for (int a = 0; a < 4; ++a)
#pragma unroll
    for (int b = 0; b < 4; ++b) acc[a][b] = (f32x4)0.0f;

  for (int kt = 0; kt < NKT_DN; ++kt) {
    int k0 = kt * BK;
#pragma unroll
    for (int j = 0; j < 4; ++j) {
      gld16(agp[j] + k0, &As[wid * 32 + j * 8][0]);
      gld16(bgp[j] + k0, &Bs[wid * 32 + j * 8][0]);
    }
    __syncthreads();
#pragma unroll
    for (int ks = 0; ks < 2; ++ks) {
      bhalf8 af[4], bf[4];
#pragma unroll
      for (int mf = 0; mf < 4; ++mf) {
        int row = wm * 64 + mf * 16 + l15;
        int c = (ks * 4 + l16) ^ (row & 7);
        af[mf] = *(const bhalf8*)&As[row][c * 8];
      }
#pragma unroll
      for (int nf = 0; nf < 4; ++nf) {
        int row = wn * 64 + nf * 16 + l15;
        int c = (ks * 4 + l16) ^ (row & 7);
        bf[nf] = *(const bhalf8*)&Bs[row][c * 8];
      }
#pragma unroll
      for (int mf = 0; mf < 4; ++mf)
#pragma unroll
        for (int nf = 0; nf < 4; ++nf)
          acc[mf][nf] = __builtin_amdgcn_mfma_f32_16x16x32_bf16(af[mf], bf[nf], acc[mf][nf], 0, 0, 0);
    }
    __syncthreads();
  }

#pragma unroll
  for (int mf = 0; mf < 4; ++mf) {
#pragma unroll
    for (int j = 0; j < 4; ++j) {
      int lm = wm * 64 + mf * 16 + l16 * 4 + j;
      if (lm < nrows) {
        int tok = token_idx[row0 + lm];
        size_t base = (size_t)tok * HH + h0 + wn * 64 + l15;
#pragma unroll
        for (int nf = 0; nf < 4; ++nf)
          atomicAdd(&out[base + nf * 16], acc[mf][nf][j]);
      }
    }
  }
}

extern "C" void kernel_launch(void* const* d_in, const int* in_sizes, int n_in,
                              void* d_out, int out_size, void* d_ws, size_t ws_size,
                              hipStream_t stream) {
  const int* sel = (const int*)d_in[0];
  const float* hs = (const float*)d_in[1];
  const float* rw = (const float*)d_in[2];
  const float* gw = (const float*)d_in[3];
  const float* uw = (const float*)d_in[4];
  const float* dw = (const float*)d_in[5];
  float* out = (float*)d_out;

  char* ws = (char*)d_ws;
  size_t o = 0;
  u16* hsb = (u16*)(ws + o); o += (size_t)TT * HH * 2;           // 32 MB
  u16* gwt = (u16*)(ws + o); o += (size_t)NE * HH * II * 2;      // 44 MB
  u16* uwt = (u16*)(ws + o); o += (size_t)NE * HH * II * 2;      // 44 MB
  u16* dwt = (u16*)(ws + o); o += (size_t)NE * HH * II * 2;      // 44 MB
  u16* act = (u16*)(ws + o); o += (size_t)NROWS * II * 2;        // 44 MB
  int* token_idx = (int*)(ws + o); o += (size_t)NROWS * 4;
  float* wrow = (float*)(ws + o); o += (size_t)NROWS * 4;
  int* s_e = (int*)(ws + o); o += MAX_SLOTS * 4;
  int* s_rs = (int*)(ws + o); o += MAX_SLOTS * 4;
  int* s_rows = (int*)(ws + o); o += MAX_SLOTS * 4;
  (void)ws_size; (void)in_sizes; (void)n_in; (void)out_size;

  // stage 1: routing + hs cvt + gate/up transpose
  k_prep<<<NB_PREP, 256, 0, stream>>>(sel, rw, hs, gw, uw,
                                      hsb, gwt, uwt,
                                      token_idx, wrow, s_e, s_rs, s_rows);

  // stage 2: gate/up GEMM + SwiGLU, with down-transpose + out-zero tail blocks
  k_gu<<<NBG_ALL, 256, 0, stream>>>(hsb, gwt, uwt, token_idx, wrow,
                                    s_e, s_rs, s_rows, act, dw, dwt, out);

  // stage 3: down GEMM with scatter-add
  k_down<<<MAX_SLOTS * NYT_DN, 256, 0, stream>>>(act, dwt, token_idx,
                                                 s_e, s_rs, s_rows, out);
}

// Round 15
// 527.394 us; speedup vs baseline: 6.1260x; 1.0066x over previous
//
#include <hip/hip_runtime.h>
#include <stdint.h>

// Problem constants (fixed shapes)
#define TT 8192      // tokens = B*S
#define HH 2048      // hidden dim
#define II 1408      // intermediate dim
#define NE 8         // experts
#define NROWS (TT*2) // (token, slot) rows = 16384
#define BM 128       // row tile
#define BK 64        // k tile
#define BND 128      // k_down N tile
#define MAX_SLOTS 144
#define NKT_GU (HH/BK)   // 32
#define NKT_DN (II/BK)   // 22
#define NYT_GU (II/64)   // 22  N-tiles in k_gu
#define NYT_DN (HH/BND)  // 16  N-tiles in k_down
#define SPX (MAX_SLOTS/8)  // 18 slots per XCD

// k_prep block ranges: routing + hs cvt + gate/up transpose only
#define NB_CVT 8192                  // (TT*HH)/2048
#define NB_T2  (22*32*16)            // 11264 gate+up transpose
#define B0_CVT 1
#define B0_T2  (B0_CVT + NB_CVT)     // 8193
#define NB_PREP (B0_T2 + NB_T2)      // 19457

// k_gu tail blocks: down transpose + output zeroing (needed only by k_down)
#define NBG (MAX_SLOTS*NYT_GU)       // 3168 GEMM blocks
#define NB_TD (32*22*8)              // 5632 down transpose
#define NB_Z  512                    // zero blocks (grid-stride)
#define NBG_ALL (NBG + NB_TD + NB_Z) // 9312

typedef unsigned short u16;
typedef __attribute__((ext_vector_type(8))) __bf16 bhalf8;
typedef __attribute__((ext_vector_type(4))) float f32x4;
typedef __attribute__((ext_vector_type(4))) float float4v;
typedef __attribute__((ext_vector_type(4))) int int4v;

__device__ __forceinline__ u16 f2bf(float f) {
  union { float f; unsigned u; } v; v.f = f;
  return (u16)((v.u + 0x7FFFu + ((v.u >> 16) & 1u)) >> 16);  // RNE
}

__device__ __forceinline__ void gld16(const void* g, void* l) {
  __builtin_amdgcn_global_load_lds(
      (const __attribute__((address_space(1))) unsigned int*)g,
      (__attribute__((address_space(3))) unsigned int*)l, 16, 0, 0);
}

// ---------------- preprocessing: route + hs cvt + gate/up transpose ------------
__global__ __launch_bounds__(256) void k_prep(const int* __restrict__ sel,
                                              const float* __restrict__ rw,
                                              const float* __restrict__ hs,
                                              const float* __restrict__ gw,
                                              const float* __restrict__ uw,
                                              u16* __restrict__ hsb,
                                              u16* __restrict__ gwt,
                                              u16* __restrict__ uwt,
                                              int* __restrict__ token_idx,
                                              float* __restrict__ wrow,
                                              int* __restrict__ s_e,
                                              int* __restrict__ s_rs,
                                              int* __restrict__ s_rows) {
  int b = blockIdx.x;
  int tid = threadIdx.x;

  if (b == 0) {
    __shared__ int cnt[NE], offs[NE + 1], cursor[NE];
    if (tid < NE) cnt[tid] = 0;
    __syncthreads();
    for (int i = tid; i < NROWS; i += 256) atomicAdd(&cnt[sel[i]], 1);
    __syncthreads();
    if (tid == 0) {
      int o = 0;
      for (int e = 0; e < NE; ++e) { offs[e] = o; o += cnt[e]; }
      offs[NE] = o;
      int ns = 0;
      for (int e = 0; e < NE; ++e) {
        for (int t = 0; t < cnt[e]; t += BM) {
          s_e[ns] = e;
          s_rs[ns] = offs[e] + t;
          s_rows[ns] = (cnt[e] - t < BM) ? (cnt[e] - t) : BM;
          ns++;
        }
      }
      for (; ns < MAX_SLOTS; ++ns) s_rows[ns] = 0;
    }
    __syncthreads();
    if (tid < NE) cursor[tid] = offs[tid];
    __syncthreads();
    for (int i = tid; i < NROWS; i += 256) {
      int e = sel[i];
      int r = atomicAdd(&cursor[e], 1);
      token_idx[r] = i >> 1;
      wrow[r] = rw[i];
    }
    return;
  }

  if (b < B0_T2) {
    size_t i = ((size_t)(b - B0_CVT) * 256 + tid) * 8;
    float4v a = *(const float4v*)(hs + i);
    float4v c = *(const float4v*)(hs + i + 4);
    u16 o[8];
    o[0] = f2bf(a.x); o[1] = f2bf(a.y); o[2] = f2bf(a.z); o[3] = f2bf(a.w);
    o[4] = f2bf(c.x); o[5] = f2bf(c.y); o[6] = f2bf(c.z); o[7] = f2bf(c.w);
    *(int4v*)(hsb + i) = *(const int4v*)o;
    return;
  }

  // gate/up transpose+cvt: x=II/64=22, y=HH/64=32, z=16
  __shared__ float t[64][65];
  int idx = b - B0_T2;
  int x = idx % 22, y = (idx / 22) % 32, z = idx / (22 * 32);
  int e = z & 7;
  const int R = HH, C = II;
  const float* ip = ((z < 8) ? gw : uw) + (size_t)e * R * C;
  u16* op = ((z < 8) ? gwt : uwt) + (size_t)e * R * C;
  int r0 = y * 64, c0 = x * 64;
  int rr = tid >> 4, c4 = (tid & 15) * 4;
#pragma unroll
  for (int j = 0; j < 4; ++j) {
    float4v v = *(const float4v*)&ip[(size_t)(r0 + rr + 16 * j) * C + c0 + c4];
    t[rr + 16 * j][c4 + 0] = v.x;
    t[rr + 16 * j][c4 + 1] = v.y;
    t[rr + 16 * j][c4 + 2] = v.z;
    t[rr + 16 * j][c4 + 3] = v.w;
  }
  __syncthreads();
  int cc = tid >> 2, rb = (tid & 3) * 16;
  u16 buf[16];
#pragma unroll
  for (int i = 0; i < 16; ++i) buf[i] = f2bf(t[rb + i][cc]);
  u16* p = op + (size_t)(c0 + cc) * R + r0 + rb;
  *(int4v*)p = *(const int4v*)&buf[0];
  *(int4v*)(p + 8) = *(const int4v*)&buf[8];
}

// ---------------- gate/up GEMM + SwiGLU, with tail blocks ----------------
// Blocks [0,NBG): GEMM (m97 structure, XCD swizzle, ytile-major).
// Blocks [NBG,NBG+NB_TD): down-weight transpose. Last: zero d_out.
__global__ __launch_bounds__(256, 4) void k_gu(const u16* __restrict__ hsb,
                                               const u16* __restrict__ gwt,
                                               const u16* __restrict__ uwt,
                                               const int* __restrict__ token_idx,
                                               const float* __restrict__ wrow,
                                               const int* __restrict__ s_e,
                                               const int* __restrict__ s_rs,
                                               const int* __restrict__ s_rows,
                                               u16* __restrict__ act,
                                               const float* __restrict__ dw,
                                               u16* __restrict__ dwt,
                                               float* __restrict__ outz) {
  __shared__ alignas(16) char smem[32768];
  int f = blockIdx.x;
  int tid = threadIdx.x;

  if (f >= NBG) {
    int b = f - NBG;
    if (b < NB_TD) {
      // ---- down transpose+cvt: x=HH/64=32, y=II/64=22, z=8 ----
      float (*t)[65] = (float(*)[65])smem;
      int x = b % 32, y = (b / 32) % 22, z = b / (32 * 22);
      const int R = II, C = HH;
      const float* ip = dw + (size_t)z * R * C;
      u16* op = dwt + (size_t)z * R * C;
      int r0 = y * 64, c0 = x * 64;
      int rr = tid >> 4, c4 = (tid & 15) * 4;
#pragma unroll
      for (int j = 0; j < 4; ++j) {
        float4v v = *(const float4v*)&ip[(size_t)(r0 + rr + 16 * j) * C + c0 + c4];
        t[rr + 16 * j][c4 + 0] = v.x;
        t[rr + 16 * j][c4 + 1] = v.y;
        t[rr + 16 * j][c4 + 2] = v.z;
        t[rr + 16 * j][c4 + 3] = v.w;
      }
      __syncthreads();
      int cc = tid >> 2, rb = (tid & 3) * 16;
      u16 buf[16];
#pragma unroll
      for (int i = 0; i < 16; ++i) buf[i] = f2bf(t[rb + i][cc]);
      u16* p = op + (size_t)(c0 + cc) * R + r0 + rb;
      *(int4v*)p = *(const int4v*)&buf[0];
      *(int4v*)(p + 8) = *(const int4v*)&buf[8];
    } else {
      int4v zv = (int4v)0;
      size_t n4 = (size_t)TT * HH / 4;
      for (size_t i = (size_t)(b - NB_TD) * 256 + tid; i < n4;
           i += (size_t)NB_Z * 256)
        ((int4v*)outz)[i] = zv;
    }
    return;
  }

  // ---- GEMM path (LDS via union) ----
  u16 (*As)[BK] = (u16(*)[BK])(smem);           // 16 KB
  u16 (*Bg)[BK] = (u16(*)[BK])(smem + 16384);   // 8 KB
  u16 (*Bu)[BK] = (u16(*)[BK])(smem + 24576);   // 8 KB

  int xcd = f & 7;
  int pos = f >> 3;                 // 0..395
  int slot = xcd * SPX + pos % SPX; // ytile-major
  int ytile = pos / SPX;
  int nrows = s_rows[slot];
  if (nrows == 0) return;
  int e = s_e[slot];
  int row0 = s_rs[slot];
  int i0 = ytile * 64;

  int lane = tid & 63;
  int wid = tid >> 6;
  int l8 = lane >> 3;
  int c8 = lane & 7;
  int cs = c8 ^ l8;            // swizzled source chunk (dest LDS linear, rule #21)

  const u16* agp[4];
#pragma unroll
  for (int j = 0; j < 4; ++j) {
    int gr = row0 + wid * 32 + j * 8 + l8;
    if (gr > NROWS - 1) gr = NROWS - 1;
    int tok = token_idx[gr];
    agp[j] = hsb + (size_t)tok * HH + cs * 8;
  }
  const u16* ggp[2]; const u16* ugp[2];
#pragma unroll
  for (int j = 0; j < 2; ++j) {
    size_t off = ((size_t)e * II + i0 + wid * 16 + j * 8 + l8) * HH + cs * 8;
    ggp[j] = gwt + off;
    ugp[j] = uwt + off;
  }

  int wm = wid >> 1, wn = wid & 1;
  int l15 = lane & 15, l16 = lane >> 4;

  f32x4 accg[4][2], accu[4][2];
#pragma unroll
  for (int a = 0; a < 4; ++a)
#pragma unroll
    for (int b2 = 0; b2 < 2; ++b2) { accg[a][b2] = (f32x4)0.0f; accu[a][b2] = (f32x4)0.0f; }

  for (int kt = 0; kt < NKT_GU; ++kt) {
    int k0 = kt * BK;
#pragma unroll
    for (int j = 0; j < 4; ++j) gld16(agp[j] + k0, &As[wid * 32 + j * 8][0]);
#pragma unroll
    for (int j = 0; j < 2; ++j) {
      gld16(ggp[j] + k0, &Bg[wid * 16 + j * 8][0]);
      gld16(ugp[j] + k0, &Bu[wid * 16 + j * 8][0]);
    }
    __syncthreads();
#pragma unroll
    for (int ks = 0; ks < 2; ++ks) {
      bhalf8 af[4], bgf[2], buf_[2];
#pragma unroll
      for (int mf = 0; mf < 4; ++mf) {
        int row = wm * 64 + mf * 16 + l15;
        int c = (ks * 4 + l16) ^ (row & 7);
        af[mf] = *(const bhalf8*)&As[row][c * 8];
      }
#pragma unroll
      for (int nf = 0; nf < 2; ++nf) {
        int row = wn * 32 + nf * 16 + l15;
        int c = (ks * 4 + l16) ^ (row & 7);
        bgf[nf] = *(const bhalf8*)&Bg[row][c * 8];
        buf_[nf] = *(const bhalf8*)&Bu[row][c * 8];
      }
#pragma unroll
      for (int mf = 0; mf < 4; ++mf)
#pragma unroll
        for (int nf = 0; nf < 2; ++nf) {
          accg[mf][nf] = __builtin_amdgcn_mfma_f32_16x16x32_bf16(af[mf], bgf[nf], accg[mf][nf], 0, 0, 0);
          accu[mf][nf] = __builtin_amdgcn_mfma_f32_16x16x32_bf16(af[mf], buf_[nf], accu[mf][nf], 0, 0, 0);
        }
    }
    __syncthreads();
  }

  // epilogue: act = w * silu(g) * u
#pragma unroll
  for (int mf = 0; mf < 4; ++mf) {
#pragma unroll
    for (int j = 0; j < 4; ++j) {
      int lm = wm * 64 + mf * 16 + l16 * 4 + j;
      if (lm < nrows) {
        int gr = row0 + lm;
        float w = wrow[gr];
        size_t base = (size_t)gr * II + i0 + wn * 32 + l15;
#pragma unroll
        for (int nf = 0; nf < 2; ++nf) {
          float g = accg[mf][nf][j];
          float u = accu[mf][nf][j];
          float s = g / (1.0f + __expf(-g));
          act[base + nf * 16] = f2bf(s * u * w);
        }
      }
    }
  }
}

// ---------------- down GEMM (BN=128) + scatter-add ----------------
// (256,4): 32 KB LDS x 4 = 128 KB, 128-reg/wave budget = 64 acc + 64 arch,
// same footprint that compiles clean in k_gu -> 16 waves/CU (was 12 at ,3).
__global__ __launch_bounds__(256, 4) void k_down(const u16* __restrict__ act,
                                                 const u16* __restrict__ dwt,
                                                 const int* __restrict__ token_idx,
                                                 const int* __restrict__ s_e,
                                                 const int* __restrict__ s_rs,
                                                 const int* __restrict__ s_rows,
                                                 float* __restrict__ out) {
  int f = blockIdx.x;
  int xcd = f & 7;
  int pos = f >> 3;                 // 0..287
  int slot = xcd * SPX + pos % SPX; // ytile-major
  int ytile = pos / SPX;
  int nrows = s_rows[slot];
  if (nrows == 0) return;
  int e = s_e[slot];
  int row0 = s_rs[slot];
  int h0 = ytile * BND;

  __shared__ alignas(16) u16 As[BM][BK];    // 16 KB
  __shared__ alignas(16) u16 Bs[BND][BK];   // 16 KB -> 32 KB total

  int tid = threadIdx.x;
  int lane = tid & 63;
  int wid = tid >> 6;
  int l8 = lane >> 3;
  int c8 = lane & 7;
  int cs = c8 ^ l8;

  const u16* agp[4];
#pragma unroll
  for (int j = 0; j < 4; ++j) {
    int gr = row0 + wid * 32 + j * 8 + l8;
    if (gr > NROWS - 1) gr = NROWS - 1;
    agp[j] = act + (size_t)gr * II + cs * 8;
  }
  const u16* bgp[4];
#pragma unroll
  for (int j = 0; j < 4; ++j)
    bgp[j] = dwt + ((size_t)e * HH + h0 + wid * 32 + j * 8 + l8) * II + cs * 8;

  int wm = wid >> 1, wn = wid & 1;
  int l15 = lane & 15, l16 = lane >> 4;

  f32x4 acc[4][4];
#pragma unroll
  for (int a = 0; a < 4; ++a)
#pragma unroll
    for (int b = 0; b < 4; ++b) acc[a][b] = (f32x4)0.0f;

  for (int kt = 0; kt < NKT_DN; ++kt) {
    int k0 = kt * BK;
#pragma unroll
    for (int j = 0; j < 4; ++j) {
      gld16(agp[j] + k0, &As[wid * 32 + j * 8][0]);
      gld16(bgp[j] + k0, &Bs[wid * 32 + j * 8][0]);
    }
    __syncthreads();
#pragma unroll
    for (int ks = 0; ks < 2; ++ks) {
      bhalf8 af[4], bf[4];
#pragma unroll
      for (int mf = 0; mf < 4; ++mf) {
        int row = wm * 64 + mf * 16 + l15;
        int c = (ks * 4 + l16) ^ (row & 7);
        af[mf] = *(const bhalf8*)&As[row][c * 8];
      }
#pragma unroll
      for (int nf = 0; nf < 4; ++nf) {
        int row = wn * 64 + nf * 16 + l15;
        int c = (ks * 4 + l16) ^ (row & 7);
        bf[nf] = *(const bhalf8*)&Bs[row][c * 8];
      }
#pragma unroll
      for (int mf = 0; mf < 4; ++mf)
#pragma unroll
        for (int nf = 0; nf < 4; ++nf)
          acc[mf][nf] = __builtin_amdgcn_mfma_f32_16x16x32_bf16(af[mf], bf[nf], acc[mf][nf], 0, 0, 0);
    }
    __syncthreads();
  }

#pragma unroll
  for (int mf = 0; mf < 4; ++mf) {
#pragma unroll
    for (int j = 0; j < 4; ++j) {
      int lm = wm * 64 + mf * 16 + l16 * 4 + j;
      if (lm < nrows) {
        int tok = token_idx[row0 + lm];
        size_t base = (size_t)tok * HH + h0 + wn * 64 + l15;
#pragma unroll
        for (int nf = 0; nf < 4; ++nf)
          atomicAdd(&out[base + nf * 16], acc[mf][nf][j]);
      }
    }
  }
}

extern "C" void kernel_launch(void* const* d_in, const int* in_sizes, int n_in,
                              void* d_out, int out_size, void* d_ws, size_t ws_size,
                              hipStream_t stream) {
  const int* sel = (const int*)d_in[0];
  const float* hs = (const float*)d_in[1];
  const float* rw = (const float*)d_in[2];
  const float* gw = (const float*)d_in[3];
  const float* uw = (const float*)d_in[4];
  const float* dw = (const float*)d_in[5];
  float* out = (float*)d_out;

  char* ws = (char*)d_ws;
  size_t o = 0;
  u16* hsb = (u16*)(ws + o); o += (size_t)TT * HH * 2;           // 32 MB
  u16* gwt = (u16*)(ws + o); o += (size_t)NE * HH * II * 2;      // 44 MB
  u16* uwt = (u16*)(ws + o); o += (size_t)NE * HH * II * 2;      // 44 MB
  u16* dwt = (u16*)(ws + o); o += (size_t)NE * HH * II * 2;      // 44 MB
  u16* act = (u16*)(ws + o); o += (size_t)NROWS * II * 2;        // 44 MB
  int* token_idx = (int*)(ws + o); o += (size_t)NROWS * 4;
  float* wrow = (float*)(ws + o); o += (size_t)NROWS * 4;
  int* s_e = (int*)(ws + o); o += MAX_SLOTS * 4;
  int* s_rs = (int*)(ws + o); o += MAX_SLOTS * 4;
  int* s_rows = (int*)(ws + o); o += MAX_SLOTS * 4;
  (void)ws_size; (void)in_sizes; (void)n_in; (void)out_size;

  // stage 1: routing + hs cvt + gate/up transpose
  k_prep<<<NB_PREP, 256, 0, stream>>>(sel, rw, hs, gw, uw,
                                      hsb, gwt, uwt,
                                      token_idx, wrow, s_e, s_rs, s_rows);

  // stage 2: gate/up GEMM + SwiGLU, with down-transpose + out-zero tail blocks
  k_gu<<<NBG_ALL, 256, 0, stream>>>(hsb, gwt, uwt, token_idx, wrow,
                                    s_e, s_rs, s_rows, act, dw, dwt, out);

  // stage 3: down GEMM with scatter-add
  k_down<<<MAX_SLOTS * NYT_DN, 256, 0, stream>>>(act, dwt, token_idx,
                                                 s_e, s_rs, s_rows, out);
}